// Round 1
// baseline (255.354 us; speedup 1.0000x reference)
//
#include <hip/hip_runtime.h>

// Problem geometry (compile-time constants from the reference):
// x: (128, 55, 55, 96) NHWC fp32; kernel: (96, 5, 5) fp32 depthwise; out = x + dwconv(x,k)
#define NB 128
#define HW 55
#define IMG (HW * HW)          // 3025
#define CH 96
#define GROUPS (CH / 4)        // 24 float4 channel-groups
#define TAPS 25
#define WSTRIDE CH             // 96 floats
#define HSTRIDE (HW * CH)      // 5280 floats

// ---- Kernel A: repack weights tap-major (float4 per group) + per-group flags ----
// wsf[tap*CH + c] = k[c*TAPS + tap]  (so group g tap t is a float4 at wsf + (t*GROUPS+g)*4)
// flags[g] = any nonzero weight among channels 4g..4g+3
__global__ void repack_kernel(const float* __restrict__ k,
                              float* __restrict__ wsf,
                              int* __restrict__ flags) {
    int tid = threadIdx.x;
    for (int idx = tid; idx < CH * TAPS; idx += blockDim.x) {
        int c = idx / TAPS;
        int tap = idx - c * TAPS;
        wsf[tap * CH + c] = k[idx];
    }
    if (tid < GROUPS) {
        int any = 0;
        for (int c = 4 * tid; c < 4 * tid + 4; ++c)
            for (int tap = 0; tap < TAPS; ++tap)
                any |= (k[c * TAPS + tap] != 0.0f) ? 1 : 0;
        flags[tid] = any;
    }
}

// ---- Kernel B: fused residual depthwise conv ----
// One thread = one (pixel, channel-group) float4. Consecutive threads -> consecutive
// groups -> fully contiguous 16B/lane coalesced access.
template <bool USE_WS>
__global__ __launch_bounds__(256) void conv_kernel(const float* __restrict__ x,
                                                   const float4* __restrict__ wts,
                                                   const int* __restrict__ flags,
                                                   const float* __restrict__ kraw,
                                                   float* __restrict__ out) {
    int t = blockIdx.x * 256 + threadIdx.x;          // grid is exact, no tail
    int g = t % GROUPS;
    int pixel = t / GROUPS;
    int n = pixel / IMG;
    int rem = pixel - n * IMG;
    int h = rem / HW;
    int w = rem - h * HW;

    int base = pixel * CH + g * 4;                   // fits in int32 (max ~37.2M)
    const float4 xc = *reinterpret_cast<const float4*>(x + base);
    float4 acc = make_float4(0.f, 0.f, 0.f, 0.f);

    bool do_conv = USE_WS ? (flags[g] != 0) : true;
    if (do_conv) {
#pragma unroll
        for (int dh = -2; dh <= 2; ++dh) {
#pragma unroll
            for (int dw = -2; dw <= 2; ++dw) {
                const int tap = (dh + 2) * 5 + (dw + 2);
                float4 wv;
                if (USE_WS) {
                    wv = wts[tap * GROUPS + g];
                } else {
                    wv.x = kraw[(g * 4 + 0) * TAPS + tap];
                    wv.y = kraw[(g * 4 + 1) * TAPS + tap];
                    wv.z = kraw[(g * 4 + 2) * TAPS + tap];
                    wv.w = kraw[(g * 4 + 3) * TAPS + tap];
                }
                bool wnz = (wv.x != 0.f) | (wv.y != 0.f) | (wv.z != 0.f) | (wv.w != 0.f);
                bool valid = ((unsigned)(h + dh) < (unsigned)HW) &
                             ((unsigned)(w + dw) < (unsigned)HW);
                if (wnz & valid) {
                    const float4 xv = *reinterpret_cast<const float4*>(
                        x + base + (dh * HSTRIDE + dw * WSTRIDE));
                    acc.x += wv.x * xv.x;
                    acc.y += wv.y * xv.y;
                    acc.z += wv.z * xv.z;
                    acc.w += wv.w * xv.w;
                }
            }
        }
    }

    float4 o = make_float4(xc.x + acc.x, xc.y + acc.y, xc.z + acc.z, xc.w + acc.w);
    *reinterpret_cast<float4*>(out + base) = o;
}

extern "C" void kernel_launch(void* const* d_in, const int* in_sizes, int n_in,
                              void* d_out, int out_size, void* d_ws, size_t ws_size,
                              hipStream_t stream) {
    const float* x = (const float*)d_in[0];
    const float* k = (const float*)d_in[1];
    float* out = (float*)d_out;

    const int total = NB * IMG * GROUPS;             // 9,292,800
    const int blocks = total / 256;                  // 36,300 (exact)

    const size_t ws_need = (size_t)(CH * TAPS) * sizeof(float) + GROUPS * sizeof(int);
    if (ws_size >= ws_need) {
        float* wsf = (float*)d_ws;
        int* flags = (int*)(wsf + CH * TAPS);
        repack_kernel<<<1, 256, 0, stream>>>(k, wsf, flags);
        conv_kernel<true><<<blocks, 256, 0, stream>>>(
            x, (const float4*)wsf, flags, k, out);
    } else {
        conv_kernel<false><<<blocks, 256, 0, stream>>>(
            x, nullptr, nullptr, k, out);
    }
}

// Round 2
// 246.788 us; speedup vs baseline: 1.0347x; 1.0347x over previous
//
#include <hip/hip_runtime.h>

// x: (128, 55, 55, 96) NHWC fp32; kernel: (96, 5, 5) fp32 depthwise; out = x + dwconv(x,k)
#define NB 128
#define HW 55
#define IMG (HW * HW)          // 3025
#define CH 96
#define GROUPS (CH / 4)        // 24 float4 channel-groups
#define TAPS 25
#define WSTRIDE CH             // 96 floats
#define HSTRIDE (HW * CH)      // 5280 floats
#define NPIX (NB * IMG)        // 387,200 pixels
#define TOTALF4 (NPIX * GROUPS) // 9,292,800 float4s

// ---- Kernel A: repack weights tap-major + build compacted active-group list ----
// wsf[tap*CH + c] = k[c*TAPS + tap]; meta[0] = nact; order[0..nact) = active groups,
// order[nact..24) = inactive groups.
__global__ void repack_kernel(const float* __restrict__ k,
                              float* __restrict__ wsf,
                              int* __restrict__ meta,
                              int* __restrict__ order) {
    int tid = threadIdx.x;
    for (int idx = tid; idx < CH * TAPS; idx += blockDim.x) {
        int c = idx / TAPS;
        int tap = idx - c * TAPS;
        wsf[tap * CH + c] = k[idx];
    }
    if (tid == 0) {
        int na = 0;
        for (int g = 0; g < GROUPS; ++g) {
            bool any = false;
            for (int c = 4 * g; c < 4 * g + 4; ++c)
                for (int t = 0; t < TAPS; ++t) any |= (k[c * TAPS + t] != 0.0f);
            if (any) order[na++] = g;
        }
        int ni = na;
        for (int g = 0; g < GROUPS; ++g) {
            bool any = false;
            for (int c = 4 * g; c < 4 * g + 4; ++c)
                for (int t = 0; t < TAPS; ++t) any |= (k[c * TAPS + t] != 0.0f);
            if (!any) order[ni++] = g;
        }
        meta[0] = na;
    }
}

// ---- Kernel B: pure residual copy, branch-free, full-BW stream ----
__global__ __launch_bounds__(256) void copy_kernel(const float4* __restrict__ x,
                                                   float4* __restrict__ out) {
    int stride = gridDim.x * blockDim.x;
    for (int i = blockIdx.x * blockDim.x + threadIdx.x; i < TOTALF4; i += stride)
        out[i] = x[i];
}

// ---- Kernel C: sparse conv — only (pixel, active-group) items; overwrites out ----
// Branchless 25-tap: invalid-boundary taps get weight*0; all loads independent.
__global__ __launch_bounds__(256) void sconv_kernel(const float* __restrict__ x,
                                                    const float4* __restrict__ wts,
                                                    const int* __restrict__ meta,
                                                    const int* __restrict__ order,
                                                    float* __restrict__ out) {
    const int nact = meta[0];
    const int total = NPIX * nact;
    const int stride = gridDim.x * blockDim.x;
    for (int t = blockIdx.x * blockDim.x + threadIdx.x; t < total; t += stride) {
        int pixel = t / nact;
        int gi = t - pixel * nact;
        int g = order[gi];
        int n = pixel / IMG;
        int rem = pixel - n * IMG;
        int h = rem / HW;
        int w = rem - h * HW;

        int base = pixel * CH + g * 4;
        const float4 xc = *reinterpret_cast<const float4*>(x + base);
        float4 acc = make_float4(xc.x, xc.y, xc.z, xc.w);

#pragma unroll
        for (int dh = -2; dh <= 2; ++dh) {
#pragma unroll
            for (int dw = -2; dw <= 2; ++dw) {
                const int tap = (dh + 2) * 5 + (dw + 2);
                const bool valid = ((unsigned)(h + dh) < (unsigned)HW) &
                                   ((unsigned)(w + dw) < (unsigned)HW);
                const float vs = valid ? 1.0f : 0.0f;
                const int off = valid ? (dh * HSTRIDE + dw * WSTRIDE) : 0;
                const float4 wv = wts[tap * GROUPS + g];
                const float4 xv = *reinterpret_cast<const float4*>(x + base + off);
                acc.x += (wv.x * vs) * xv.x;
                acc.y += (wv.y * vs) * xv.y;
                acc.z += (wv.z * vs) * xv.z;
                acc.w += (wv.w * vs) * xv.w;
            }
        }
        *reinterpret_cast<float4*>(out + base) = acc;
    }
}

// ---- Fallback (ws too small): monolithic, reads raw k — correctness only ----
__global__ __launch_bounds__(256) void fallback_kernel(const float* __restrict__ x,
                                                       const float* __restrict__ kraw,
                                                       float* __restrict__ out) {
    int t = blockIdx.x * 256 + threadIdx.x;
    if (t >= TOTALF4) return;
    int g = t % GROUPS;
    int pixel = t / GROUPS;
    int n = pixel / IMG;
    int rem = pixel - n * IMG;
    int h = rem / HW;
    int w = rem - h * HW;
    int base = pixel * CH + g * 4;
    const float4 xc = *reinterpret_cast<const float4*>(x + base);
    float4 acc = make_float4(xc.x, xc.y, xc.z, xc.w);
#pragma unroll
    for (int dh = -2; dh <= 2; ++dh)
#pragma unroll
        for (int dw = -2; dw <= 2; ++dw) {
            const int tap = (dh + 2) * 5 + (dw + 2);
            const bool valid = ((unsigned)(h + dh) < (unsigned)HW) &
                               ((unsigned)(w + dw) < (unsigned)HW);
            const float vs = valid ? 1.0f : 0.0f;
            const int off = valid ? (dh * HSTRIDE + dw * WSTRIDE) : 0;
            const float4 xv = *reinterpret_cast<const float4*>(x + base + off);
            acc.x += (kraw[(g * 4 + 0) * TAPS + tap] * vs) * xv.x;
            acc.y += (kraw[(g * 4 + 1) * TAPS + tap] * vs) * xv.y;
            acc.z += (kraw[(g * 4 + 2) * TAPS + tap] * vs) * xv.z;
            acc.w += (kraw[(g * 4 + 3) * TAPS + tap] * vs) * xv.w;
        }
    *reinterpret_cast<float4*>(out + base) = acc;
}

extern "C" void kernel_launch(void* const* d_in, const int* in_sizes, int n_in,
                              void* d_out, int out_size, void* d_ws, size_t ws_size,
                              hipStream_t stream) {
    const float* x = (const float*)d_in[0];
    const float* k = (const float*)d_in[1];
    float* out = (float*)d_out;

    const size_t ws_need = (size_t)(CH * TAPS) * sizeof(float) + (1 + GROUPS) * sizeof(int);
    if (ws_size >= ws_need) {
        float* wsf = (float*)d_ws;
        int* meta = (int*)(wsf + CH * TAPS);
        int* order = meta + 1;

        repack_kernel<<<1, 128, 0, stream>>>(k, wsf, meta, order);
        copy_kernel<<<2048, 256, 0, stream>>>((const float4*)x, (float4*)out);
        sconv_kernel<<<1024, 256, 0, stream>>>(x, (const float4*)wsf, meta, order, out);
    } else {
        fallback_kernel<<<TOTALF4 / 256, 256, 0, stream>>>(x, k, out);
    }
}

// Round 3
// 191.852 us; speedup vs baseline: 1.3310x; 1.2863x over previous
//
#include <hip/hip_runtime.h>

// x: (128, 55, 55, 96) NHWC fp32; kernel: (96, 5, 5) fp32 depthwise; out = x + dwconv(x,k)
#define NB 128
#define HW 55
#define IMG (HW * HW)           // 3025
#define CH 96
#define GROUPS (CH / 4)         // 24 float4 channel-groups
#define TAPS 25
#define WSTRIDE CH              // 96 floats
#define HSTRIDE (HW * CH)       // 5280 floats
#define NPIX (NB * IMG)         // 387,200 pixels
#define TOTALF4 (NPIX * GROUPS) // 9,292,800 float4 items
#define NWG (TOTALF4 / 256)     // 36,300 blocks (exact)
#define NXCD 8

// ---- Kernel A: repack weights tap-major (float4/group) + per-group 25-bit tap mask ----
// wsf[tap*CH + c] = k[c*TAPS + tap]; tapmask[g] bit t set iff any of channels 4g..4g+3
// has a nonzero weight at tap t. Fully runtime-derived from the kernel input.
__global__ void repack_kernel(const float* __restrict__ k,
                              float* __restrict__ wsf,
                              int* __restrict__ tapmask) {
    int tid = threadIdx.x;
    for (int idx = tid; idx < CH * TAPS; idx += blockDim.x) {
        int c = idx / TAPS;
        int tap = idx - c * TAPS;
        wsf[tap * CH + c] = k[idx];
    }
    if (tid < GROUPS) {
        int m = 0;
        for (int tap = 0; tap < TAPS; ++tap) {
            bool any = false;
            for (int c = 4 * tid; c < 4 * tid + 4; ++c)
                any |= (k[c * TAPS + tap] != 0.0f);
            if (any) m |= (1 << tap);
        }
        tapmask[tid] = m;
    }
}

// ---- Kernel B: fused residual depthwise conv, one float4 item per thread ----
__global__ __launch_bounds__(256) void fused_kernel(const float* __restrict__ x,
                                                    const float4* __restrict__ wts,
                                                    const int* __restrict__ tapmask,
                                                    float* __restrict__ out) {
    // Bijective chunked XCD swizzle (NWG % 8 != 0 -> m204 formula):
    // each XCD gets a contiguous range of the grid for L2 h-locality.
    const int q = NWG / NXCD, r = NWG % NXCD;     // 4537, 4
    int xcd = blockIdx.x & (NXCD - 1);
    int idx = blockIdx.x >> 3;
    int swz = (xcd < r ? xcd * (q + 1) : r * (q + 1) + (xcd - r) * q) + idx;

    int t = swz * 256 + threadIdx.x;
    int g = t % GROUPS;
    int pixel = t / GROUPS;
    int rem = pixel % IMG;
    int h = rem / HW;
    int w = rem - h * HW;

    int base = pixel * CH + g * 4;
    float4 acc = *reinterpret_cast<const float4*>(x + base);   // residual

    const int tm = tapmask[g];
    if (tm) {
        // Single exec-masked region; taps skipped wave-uniformly; inside a tap
        // everything is branchless so loads are independent (ILP).
#pragma unroll
        for (int dh = -2; dh <= 2; ++dh) {
#pragma unroll
            for (int dw = -2; dw <= 2; ++dw) {
                const int tap = (dh + 2) * 5 + (dw + 2);
                if (__any((tm >> tap) & 1)) {
                    const bool valid = ((unsigned)(h + dh) < (unsigned)HW) &
                                       ((unsigned)(w + dw) < (unsigned)HW);
                    const float vs = valid ? 1.0f : 0.0f;
                    const int off = valid ? (dh * HSTRIDE + dw * WSTRIDE) : 0;
                    const float4 wv = wts[tap * GROUPS + g];
                    const float4 xv = *reinterpret_cast<const float4*>(x + base + off);
                    acc.x += (wv.x * vs) * xv.x;
                    acc.y += (wv.y * vs) * xv.y;
                    acc.z += (wv.z * vs) * xv.z;
                    acc.w += (wv.w * vs) * xv.w;
                }
            }
        }
    }
    *reinterpret_cast<float4*>(out + base) = acc;
}

// ---- Fallback (ws too small): monolithic, reads raw k — correctness only ----
__global__ __launch_bounds__(256) void fallback_kernel(const float* __restrict__ x,
                                                       const float* __restrict__ kraw,
                                                       float* __restrict__ out) {
    int t = blockIdx.x * 256 + threadIdx.x;
    if (t >= TOTALF4) return;
    int g = t % GROUPS;
    int pixel = t / GROUPS;
    int rem = pixel % IMG;
    int h = rem / HW;
    int w = rem - h * HW;
    int base = pixel * CH + g * 4;
    const float4 xc = *reinterpret_cast<const float4*>(x + base);
    float4 acc = make_float4(xc.x, xc.y, xc.z, xc.w);
#pragma unroll
    for (int dh = -2; dh <= 2; ++dh)
#pragma unroll
        for (int dw = -2; dw <= 2; ++dw) {
            const int tap = (dh + 2) * 5 + (dw + 2);
            const bool valid = ((unsigned)(h + dh) < (unsigned)HW) &
                               ((unsigned)(w + dw) < (unsigned)HW);
            const float vs = valid ? 1.0f : 0.0f;
            const int off = valid ? (dh * HSTRIDE + dw * WSTRIDE) : 0;
            const float4 xv = *reinterpret_cast<const float4*>(x + base + off);
            acc.x += (kraw[(g * 4 + 0) * TAPS + tap] * vs) * xv.x;
            acc.y += (kraw[(g * 4 + 1) * TAPS + tap] * vs) * xv.y;
            acc.z += (kraw[(g * 4 + 2) * TAPS + tap] * vs) * xv.z;
            acc.w += (kraw[(g * 4 + 3) * TAPS + tap] * vs) * xv.w;
        }
    *reinterpret_cast<float4*>(out + base) = acc;
}

extern "C" void kernel_launch(void* const* d_in, const int* in_sizes, int n_in,
                              void* d_out, int out_size, void* d_ws, size_t ws_size,
                              hipStream_t stream) {
    const float* x = (const float*)d_in[0];
    const float* k = (const float*)d_in[1];
    float* out = (float*)d_out;

    const size_t ws_need = (size_t)(CH * TAPS) * sizeof(float) + GROUPS * sizeof(int);
    if (ws_size >= ws_need) {
        float* wsf = (float*)d_ws;
        int* tapmask = (int*)(wsf + CH * TAPS);
        repack_kernel<<<1, 128, 0, stream>>>(k, wsf, tapmask);
        fused_kernel<<<NWG, 256, 0, stream>>>(x, (const float4*)wsf, tapmask, out);
    } else {
        fallback_kernel<<<NWG, 256, 0, stream>>>(x, k, out);
    }
}

// Round 4
// 124.299 us; speedup vs baseline: 2.0544x; 1.5435x over previous
//
#include <hip/hip_runtime.h>

// x: (128, 55, 55, 96) NHWC fp32; kernel: (96, 5, 5) fp32 depthwise; out = x + dwconv(x,k)
#define NB 128
#define HW 55
#define IMG (HW * HW)           // 3025
#define CH 96
#define GROUPS (CH / 4)         // 24 float4 channel-groups
#define TAPS 25
#define WSTRIDE CH              // 96 floats
#define HSTRIDE (HW * CH)       // 5280 floats
#define NPIX (NB * IMG)         // 387,200 pixels
#define TOTALF4 (NPIX * GROUPS) // 9,292,800 float4 items
#define NWG (TOTALF4 / 256)     // 36,300 blocks (exact)
#define NXCD 8
#define NSLOTCAP 32             // tap-slot capacity (>= TAPS rounded to 8)

// ---- workspace layout ----
// float4 wslot[NSLOTCAP][GROUPS]  : compacted nonzero-tap weights (pad = 0)
// int2   oslot[NSLOTCAP][GROUPS]  : {float-offset, (dh+2)<<8 | (dw+2)} (pad = {0, center})
// int    ntap[GROUPS]             : nonzero-tap count per group
// int    nslotmax                 : max ntap over groups, rounded up to multiple of 8

// ---- Kernel A: build compacted per-group tap lists (fully runtime-derived) ----
__global__ void repack_kernel(const float* __restrict__ k,
                              float4* __restrict__ wslot,
                              int2* __restrict__ oslot,
                              int* __restrict__ ntap,
                              int* __restrict__ nslotmax) {
    int g = threadIdx.x;
    if (g < GROUPS) {
        int ns = 0;
        for (int tap = 0; tap < TAPS; ++tap) {
            float w0 = k[(4 * g + 0) * TAPS + tap];
            float w1 = k[(4 * g + 1) * TAPS + tap];
            float w2 = k[(4 * g + 2) * TAPS + tap];
            float w3 = k[(4 * g + 3) * TAPS + tap];
            if (w0 != 0.f || w1 != 0.f || w2 != 0.f || w3 != 0.f) {
                int dh = tap / 5 - 2, dw = tap % 5 - 2;
                wslot[ns * GROUPS + g] = make_float4(w0, w1, w2, w3);
                oslot[ns * GROUPS + g] =
                    make_int2(dh * HSTRIDE + dw * WSTRIDE, ((dh + 2) << 8) | (dw + 2));
                ++ns;
            }
        }
        ntap[g] = ns;
        for (int s = ns; s < NSLOTCAP; ++s) {           // pads: contribute exactly 0
            wslot[s * GROUPS + g] = make_float4(0.f, 0.f, 0.f, 0.f);
            oslot[s * GROUPS + g] = make_int2(0, (2 << 8) | 2);
        }
    }
    __syncthreads();
    if (threadIdx.x == 0) {
        int m = 0;
        for (int gg = 0; gg < GROUPS; ++gg) m = m > ntap[gg] ? m : ntap[gg];
        *nslotmax = (m + 7) & ~7;                       // multiple of 8 (0 if all-zero kernel)
    }
}

// ---- Kernel B: fused residual depthwise conv, one float4 item per thread ----
// Single exec region, 8-slot unrolled branchless body -> 16 independent loads in flight.
__global__ __launch_bounds__(256) void fused_kernel(const float* __restrict__ x,
                                                    const float4* __restrict__ wslot,
                                                    const int2* __restrict__ oslot,
                                                    const int* __restrict__ ntap,
                                                    const int* __restrict__ nslotmax,
                                                    float* __restrict__ out) {
    // Bijective chunked XCD swizzle (m204): contiguous grid ranges per XCD for L2 locality.
    const int q = NWG / NXCD, r = NWG % NXCD;
    int xcd = blockIdx.x & (NXCD - 1);
    int idx = blockIdx.x >> 3;
    int swz = (xcd < r ? xcd * (q + 1) : r * (q + 1) + (xcd - r) * q) + idx;

    int t = swz * 256 + threadIdx.x;
    int g = t % GROUPS;
    int pixel = t / GROUPS;
    int rem = pixel % IMG;
    int h = rem / HW;
    int w = rem - h * HW;

    int base = pixel * CH + g * 4;
    float4 acc = *reinterpret_cast<const float4*>(x + base);   // residual

    const int nt = ntap[g];
    const int nmax = *nslotmax;
    if (nt > 0) {                                   // ONE exec-masked region
        for (int s0 = 0; s0 < nmax; s0 += 8) {
#pragma unroll
            for (int si = 0; si < 8; ++si) {
                const int s = s0 + si;
                const int2 om = oslot[s * GROUPS + g];
                const int dh2 = (om.y >> 8) & 0xFF;
                const int dw2 = om.y & 0xFF;
                const bool valid = ((unsigned)(h + dh2 - 2) < (unsigned)HW) &
                                   ((unsigned)(w + dw2 - 2) < (unsigned)HW);
                const float sc = valid ? 1.0f : 0.0f;
                const int off = valid ? om.x : 0;
                const float4 wv = wslot[s * GROUPS + g];
                const float4 xv = *reinterpret_cast<const float4*>(x + base + off);
                acc.x += (wv.x * sc) * xv.x;
                acc.y += (wv.y * sc) * xv.y;
                acc.z += (wv.z * sc) * xv.z;
                acc.w += (wv.w * sc) * xv.w;
            }
        }
    }
    // out is write-once, never re-read: nontemporal store keeps L2/L3 for x.
    __builtin_nontemporal_store(acc.x, out + base + 0);
    __builtin_nontemporal_store(acc.y, out + base + 1);
    __builtin_nontemporal_store(acc.z, out + base + 2);
    __builtin_nontemporal_store(acc.w, out + base + 3);
}

// ---- Fallback (ws too small): monolithic, reads raw k — correctness only ----
__global__ __launch_bounds__(256) void fallback_kernel(const float* __restrict__ x,
                                                       const float* __restrict__ kraw,
                                                       float* __restrict__ out) {
    int t = blockIdx.x * 256 + threadIdx.x;
    if (t >= TOTALF4) return;
    int g = t % GROUPS;
    int pixel = t / GROUPS;
    int rem = pixel % IMG;
    int h = rem / HW;
    int w = rem - h * HW;
    int base = pixel * CH + g * 4;
    const float4 xc = *reinterpret_cast<const float4*>(x + base);
    float4 acc = make_float4(xc.x, xc.y, xc.z, xc.w);
#pragma unroll
    for (int dh = -2; dh <= 2; ++dh)
#pragma unroll
        for (int dw = -2; dw <= 2; ++dw) {
            const int tap = (dh + 2) * 5 + (dw + 2);
            const bool valid = ((unsigned)(h + dh) < (unsigned)HW) &
                               ((unsigned)(w + dw) < (unsigned)HW);
            const float vs = valid ? 1.0f : 0.0f;
            const int off = valid ? (dh * HSTRIDE + dw * WSTRIDE) : 0;
            const float4 xv = *reinterpret_cast<const float4*>(x + base + off);
            acc.x += (kraw[(g * 4 + 0) * TAPS + tap] * vs) * xv.x;
            acc.y += (kraw[(g * 4 + 1) * TAPS + tap] * vs) * xv.y;
            acc.z += (kraw[(g * 4 + 2) * TAPS + tap] * vs) * xv.z;
            acc.w += (kraw[(g * 4 + 3) * TAPS + tap] * vs) * xv.w;
        }
    *reinterpret_cast<float4*>(out + base) = acc;
}

extern "C" void kernel_launch(void* const* d_in, const int* in_sizes, int n_in,
                              void* d_out, int out_size, void* d_ws, size_t ws_size,
                              hipStream_t stream) {
    const float* x = (const float*)d_in[0];
    const float* k = (const float*)d_in[1];
    float* out = (float*)d_out;

    const size_t sz_wslot = (size_t)NSLOTCAP * GROUPS * sizeof(float4);
    const size_t sz_oslot = (size_t)NSLOTCAP * GROUPS * sizeof(int2);
    const size_t sz_ntap = GROUPS * sizeof(int);
    const size_t ws_need = sz_wslot + sz_oslot + sz_ntap + sizeof(int);

    if (ws_size >= ws_need) {
        char* p = (char*)d_ws;
        float4* wslot = (float4*)p;            p += sz_wslot;
        int2* oslot = (int2*)p;                p += sz_oslot;
        int* ntap = (int*)p;                   p += sz_ntap;
        int* nslotmax = (int*)p;

        repack_kernel<<<1, 64, 0, stream>>>(k, wslot, oslot, ntap, nslotmax);
        fused_kernel<<<NWG, 256, 0, stream>>>(x, wslot, oslot, ntap, nslotmax, out);
    } else {
        fallback_kernel<<<NWG, 256, 0, stream>>>(x, k, out);
    }
}

// Round 5
// 121.054 us; speedup vs baseline: 2.1094x; 1.0268x over previous
//
#include <hip/hip_runtime.h>

// x: (128, 55, 55, 96) NHWC fp32; kernel: (96, 5, 5) fp32 depthwise; out = x + dwconv(x,k)
#define NB 128
#define HW 55
#define IMG (HW * HW)           // 3025
#define CH 96
#define GROUPS (CH / 4)         // 24 float4 channel-groups
#define TAPS 25
#define WSTRIDE CH              // 96 floats
#define HSTRIDE (HW * CH)       // 5280 floats
#define NPIX (NB * IMG)         // 387,200 pixels
#define TOTALF4 (NPIX * GROUPS) // 9,292,800 float4 items
#define NWG (TOTALF4 / 256)     // 36,300 blocks (exact)
#define NXCD 8
#define NSLOTCAP 32             // tap-slot capacity (>= TAPS rounded to 8)

// ---- workspace layout ----
// float4 wslot[NSLOTCAP][GROUPS]  : compacted nonzero-tap weights (pad = 0)
// int2   oslot[NSLOTCAP][GROUPS]  : {float-offset, (dh+2)<<8 | (dw+2)} (pad = {0, center})
// int    ntap[GROUPS]             : nonzero-tap count per group
// int    nslotmax                 : max ntap over groups, rounded up to multiple of 8

// ---- Kernel A: build compacted per-group tap lists (fully runtime-derived) ----
__global__ void repack_kernel(const float* __restrict__ k,
                              float4* __restrict__ wslot,
                              int2* __restrict__ oslot,
                              int* __restrict__ ntap,
                              int* __restrict__ nslotmax) {
    int g = threadIdx.x;
    if (g < GROUPS) {
        int ns = 0;
        for (int tap = 0; tap < TAPS; ++tap) {
            float w0 = k[(4 * g + 0) * TAPS + tap];
            float w1 = k[(4 * g + 1) * TAPS + tap];
            float w2 = k[(4 * g + 2) * TAPS + tap];
            float w3 = k[(4 * g + 3) * TAPS + tap];
            if (w0 != 0.f || w1 != 0.f || w2 != 0.f || w3 != 0.f) {
                int dh = tap / 5 - 2, dw = tap % 5 - 2;
                wslot[ns * GROUPS + g] = make_float4(w0, w1, w2, w3);
                oslot[ns * GROUPS + g] =
                    make_int2(dh * HSTRIDE + dw * WSTRIDE, ((dh + 2) << 8) | (dw + 2));
                ++ns;
            }
        }
        ntap[g] = ns;
        for (int s = ns; s < NSLOTCAP; ++s) {           // pads: contribute exactly 0
            wslot[s * GROUPS + g] = make_float4(0.f, 0.f, 0.f, 0.f);
            oslot[s * GROUPS + g] = make_int2(0, (2 << 8) | 2);
        }
    }
    __syncthreads();
    if (threadIdx.x == 0) {
        int m = 0;
        for (int gg = 0; gg < GROUPS; ++gg) m = m > ntap[gg] ? m : ntap[gg];
        *nslotmax = (m + 7) & ~7;                       // multiple of 8 (0 if all-zero kernel)
    }
}

// ---- Kernel B: fused residual depthwise conv, one float4 item per thread ----
// Batched 8-slot body with STATIC-index arrays: 8 table loads issue together,
// then 8 x-loads issue together -> ~2 latency exposures instead of 8.
__global__ __launch_bounds__(256) void fused_kernel(const float* __restrict__ x,
                                                    const float4* __restrict__ wslot,
                                                    const int2* __restrict__ oslot,
                                                    const int* __restrict__ ntap,
                                                    const int* __restrict__ nslotmax,
                                                    float* __restrict__ out) {
    // Bijective chunked XCD swizzle (m204): contiguous grid ranges per XCD for L2 locality.
    const int q = NWG / NXCD, r = NWG % NXCD;
    int xcd = blockIdx.x & (NXCD - 1);
    int idx = blockIdx.x >> 3;
    int swz = (xcd < r ? xcd * (q + 1) : r * (q + 1) + (xcd - r) * q) + idx;

    int t = swz * 256 + threadIdx.x;
    int g = t % GROUPS;
    int pixel = t / GROUPS;
    int rem = pixel % IMG;
    int h = rem / HW;
    int w = rem - h * HW;

    int base = pixel * CH + g * 4;
    float4 acc = *reinterpret_cast<const float4*>(x + base);   // residual

    const int nt = ntap[g];
    const int nmax = *nslotmax;
    if (nt > 0) {                                   // ONE exec-masked region
        const int2* orow = oslot + g;               // + s*GROUPS folds to imm offsets
        const float4* wrow = wslot + g;
        for (int s0 = 0; s0 < nmax; s0 += 8) {
            int2 om[8];
#pragma unroll
            for (int si = 0; si < 8; ++si) om[si] = orow[(s0 + si) * GROUPS];
            float4 wv[8];
#pragma unroll
            for (int si = 0; si < 8; ++si) wv[si] = wrow[(s0 + si) * GROUPS];
            float sc[8];
            float4 xv[8];
#pragma unroll
            for (int si = 0; si < 8; ++si) {
                const int dh2 = (om[si].y >> 8) & 0xFF;
                const int dw2 = om[si].y & 0xFF;
                const bool valid = ((unsigned)(h + dh2 - 2) < (unsigned)HW) &
                                   ((unsigned)(w + dw2 - 2) < (unsigned)HW);
                sc[si] = valid ? 1.0f : 0.0f;
                const int off = valid ? om[si].x : 0;
                xv[si] = *reinterpret_cast<const float4*>(x + base + off);
            }
#pragma unroll
            for (int si = 0; si < 8; ++si) {
                acc.x += (wv[si].x * sc[si]) * xv[si].x;
                acc.y += (wv[si].y * sc[si]) * xv[si].y;
                acc.z += (wv[si].z * sc[si]) * xv[si].z;
                acc.w += (wv[si].w * sc[si]) * xv[si].w;
            }
        }
    }
    // out is write-once, never re-read: nontemporal store keeps L2/L3 for x.
    __builtin_nontemporal_store(acc.x, out + base + 0);
    __builtin_nontemporal_store(acc.y, out + base + 1);
    __builtin_nontemporal_store(acc.z, out + base + 2);
    __builtin_nontemporal_store(acc.w, out + base + 3);
}

// ---- Fallback (ws too small): monolithic, reads raw k — correctness only ----
__global__ __launch_bounds__(256) void fallback_kernel(const float* __restrict__ x,
                                                       const float* __restrict__ kraw,
                                                       float* __restrict__ out) {
    int t = blockIdx.x * 256 + threadIdx.x;
    if (t >= TOTALF4) return;
    int g = t % GROUPS;
    int pixel = t / GROUPS;
    int rem = pixel % IMG;
    int h = rem / HW;
    int w = rem - h * HW;
    int base = pixel * CH + g * 4;
    const float4 xc = *reinterpret_cast<const float4*>(x + base);
    float4 acc = make_float4(xc.x, xc.y, xc.z, xc.w);
#pragma unroll
    for (int dh = -2; dh <= 2; ++dh)
#pragma unroll
        for (int dw = -2; dw <= 2; ++dw) {
            const int tap = (dh + 2) * 5 + (dw + 2);
            const bool valid = ((unsigned)(h + dh) < (unsigned)HW) &
                               ((unsigned)(w + dw) < (unsigned)HW);
            const float vs = valid ? 1.0f : 0.0f;
            const int off = valid ? (dh * HSTRIDE + dw * WSTRIDE) : 0;
            const float4 xv = *reinterpret_cast<const float4*>(x + base + off);
            acc.x += (kraw[(g * 4 + 0) * TAPS + tap] * vs) * xv.x;
            acc.y += (kraw[(g * 4 + 1) * TAPS + tap] * vs) * xv.y;
            acc.z += (kraw[(g * 4 + 2) * TAPS + tap] * vs) * xv.z;
            acc.w += (kraw[(g * 4 + 3) * TAPS + tap] * vs) * xv.w;
        }
    *reinterpret_cast<float4*>(out + base) = acc;
}

extern "C" void kernel_launch(void* const* d_in, const int* in_sizes, int n_in,
                              void* d_out, int out_size, void* d_ws, size_t ws_size,
                              hipStream_t stream) {
    const float* x = (const float*)d_in[0];
    const float* k = (const float*)d_in[1];
    float* out = (float*)d_out;

    const size_t sz_wslot = (size_t)NSLOTCAP * GROUPS * sizeof(float4);
    const size_t sz_oslot = (size_t)NSLOTCAP * GROUPS * sizeof(int2);
    const size_t sz_ntap = GROUPS * sizeof(int);
    const size_t ws_need = sz_wslot + sz_oslot + sz_ntap + sizeof(int);

    if (ws_size >= ws_need) {
        char* p = (char*)d_ws;
        float4* wslot = (float4*)p;            p += sz_wslot;
        int2* oslot = (int2*)p;                p += sz_oslot;
        int* ntap = (int*)p;                   p += sz_ntap;
        int* nslotmax = (int*)p;

        repack_kernel<<<1, 64, 0, stream>>>(k, wslot, oslot, ntap, nslotmax);
        fused_kernel<<<NWG, 256, 0, stream>>>(x, wslot, oslot, ntap, nslotmax, out);
    } else {
        fallback_kernel<<<NWG, 256, 0, stream>>>(x, k, out);
    }
}